// Round 12
// baseline (177.868 us; speedup 1.0000x reference)
//
#include <hip/hip_runtime.h>

// Problem constants (WLN_Edit): B=64, N=512, NB=600, A=89, E=5, H=256, MAX_NB=10, DEPTH=3
constexpr int Bb   = 64;
constexpr int Nn   = 512;
constexpr int NBb  = 600;
constexpr int Ad   = 89;
constexpr int Ed   = 5;
constexpr int Hd   = 256;
constexpr int MNB  = 10;
constexpr int Mrows  = Bb * Nn;    // 32768
constexpr int NBrows = Bb * NBb;   // 38400
constexpr int Kpad   = 96;

typedef __bf16 bf16x8 __attribute__((ext_vector_type(8)));
typedef float  f32x4  __attribute__((ext_vector_type(4)));

typedef __attribute__((address_space(1))) const void gvoid_t;
typedef __attribute__((address_space(3))) void lvoid_t;

__device__ inline ushort bf_rne(float x) {
  unsigned u = __float_as_uint(x);
  unsigned r = (u + 0x7fffu + ((u >> 16) & 1u)) >> 16;
  return (ushort)r;
}
__device__ inline float bf_f(ushort h) { return __uint_as_float(((unsigned)h) << 16); }

// ---------------------------------------------------------------------------
// Mega-prep (no LDS): S0 Apadh, S1 Z, S2 PIdx, S3 weight panels, S4 wabf.
// ---------------------------------------------------------------------------
constexpr int S0 = Mrows * Kpad / 256;   // 12288
constexpr int S1 = NBrows / 8;           // 4800
constexpr int S2 = Mrows * MNB / 256;    // 1280
constexpr int S3 = 256;
constexpr int S4 = Kpad * Hd / 256;      // 96

__global__ __launch_bounds__(256)
void megaprep(const float* __restrict__ input_atom, const float* __restrict__ input_bond,
              const int* __restrict__ atom_graph, const int* __restrict__ bond_graph,
              const float* __restrict__ W_atom, const float* __restrict__ W_U2,
              const float* __restrict__ b_U2, const float* __restrict__ W_U1,
              ushort* __restrict__ Apadh, ushort* __restrict__ Z, uint* __restrict__ PIdx,
              ushort* __restrict__ w2h, ushort* __restrict__ w1ah, ushort* __restrict__ w1bh,
              ushort* __restrict__ wabf) {
  const int blk = blockIdx.x;
  const int tid = threadIdx.x;
  if (blk < S0) {                                   // conv_atom
    const int e = blk * 256 + tid;
    const int m = e / Kpad, c = e - m * Kpad;
    Apadh[e] = bf_rne(c < Ad ? input_atom[(size_t)m * Ad + c] : 0.f);
  } else if (blk < S0 + S1) {                       // zprep
    const int r0 = (blk - S0) * 8;
    const int h = tid;
    float w[Ed];
#pragma unroll
    for (int e = 0; e < Ed; ++e) w[e] = W_U2[(size_t)(Hd + e) * Hd + h];
    const float b2 = b_U2[h];
#pragma unroll
    for (int j = 0; j < 8; ++j) {
      const int r = r0 + j;
      const float* bp = input_bond + (size_t)r * Ed;
      float d = b2;
#pragma unroll
      for (int e = 0; e < Ed; ++e) d = fmaf(bp[e], w[e], d);
      Z[(size_t)r * Hd + h] = bf_rne(d);
    }
  } else if (blk < S0 + S1 + S2) {                  // idxpack
    const int i = (blk - S0 - S1) * 256 + tid;
    const uint ai = (uint)atom_graph[(size_t)i * 2 + 1];
    const uint bi = (uint)bond_graph[(size_t)i * 2 + 1];
    PIdx[i] = (ai << 16) | bi;
  } else if (blk < S0 + S1 + S2 + S3) {             // transposed weight panels
    const int n = blk - S0 - S1 - S2;
    const int k = tid;
    const size_t o = (size_t)n * 256 + k;
    w2h[o]  = bf_rne(W_U2[(size_t)k * Hd + n]);
    w1ah[o] = bf_rne(W_U1[(size_t)k * Hd + n]);
    w1bh[o] = bf_rne(W_U1[(size_t)(k + 256) * Hd + n]);
  } else {                                          // S4: wabf row-major copy
    const int e = (blk - S0 - S1 - S2 - S3) * 256 + tid;   // e = a*256+h
    const int a = e >> 8, h = e & 255;
    wabf[e] = bf_rne((a < Ad) ? W_atom[(size_t)a * Hd + h] : 0.f);
  }
}

// ---------------------------------------------------------------------------
// Wcomb GEMM (4 blocks): WcT[n][a] = panel[n][:] . wabf[a][:]  (unchanged r11).
// ---------------------------------------------------------------------------
__global__ __launch_bounds__(256)
void gemm_wcomb(const ushort* __restrict__ w2h, const ushort* __restrict__ w1ah,
                const ushort* __restrict__ wabf,
                ushort* __restrict__ wc2T, ushort* __restrict__ wc1T) {
  __shared__ ushort As[2][4096];
  __shared__ ushort Bs[2][4096];
  const ushort* Apan = blockIdx.y ? w1ah : w2h;
  ushort*       Cpan = blockIdx.y ? wc1T : wc2T;
  const int tid  = threadIdx.x;
  const int lane = tid & 63;
  const int w    = tid >> 6;
  const int wr   = w >> 1, wc = w & 1;
  const int m0   = blockIdx.x * 128;
  const int arow = tid >> 2;
  const int acol = (tid & 3) * 8;
  const int fr   = lane & 15;
  const int fq   = lane >> 4;

  f32x4 acc[4][4] = {};

  auto stage = [&](int kk, int db) {
#pragma unroll
    for (int i = 0; i < 2; ++i) {
      const ushort* ga = Apan + (size_t)(m0 + arow + 64 * i) * 256 + kk + acol;
      __builtin_amdgcn_global_load_lds((gvoid_t*)ga,
          (lvoid_t*)(&As[db][i * 2048 + w * 512]), 16, 0, 0);
      const int brow = min(arow + 64 * i, Kpad - 1);
      const ushort* gb = wabf + (size_t)brow * 256 + kk + acol;
      __builtin_amdgcn_global_load_lds((gvoid_t*)gb,
          (lvoid_t*)(&Bs[db][i * 2048 + w * 512]), 16, 0, 0);
    }
  };

  stage(0, 0);
  __syncthreads();

#pragma unroll
  for (int ts = 0; ts < 8; ++ts) {
    const int db = ts & 1;
    if (ts + 1 < 8) stage((ts + 1) * 32, db ^ 1);
    bf16x8 bfr[4];
#pragma unroll
    for (int nf = 0; nf < 4; ++nf)
      bfr[nf] = *reinterpret_cast<const bf16x8*>(&Bs[db][(wc * 64 + nf * 16 + fr) * 32 + fq * 8]);
#pragma unroll
    for (int mf = 0; mf < 4; ++mf) {
      bf16x8 af = *reinterpret_cast<const bf16x8*>(&As[db][(wr * 64 + mf * 16 + fr) * 32 + fq * 8]);
#pragma unroll
      for (int nf = 0; nf < 4; ++nf)
        acc[mf][nf] = __builtin_amdgcn_mfma_f32_16x16x32_bf16(af, bfr[nf], acc[mf][nf], 0, 0, 0);
    }
    __syncthreads();
  }

#pragma unroll
  for (int mf = 0; mf < 4; ++mf) {
#pragma unroll
    for (int nf = 0; nf < 4; ++nf) {
      const int col = wc * 64 + nf * 16 + fr;
      if (col < Kpad) {
#pragma unroll
        for (int r = 0; r < 4; ++r) {
          const int row = m0 + wr * 64 + mf * 16 + fq * 4 + r;
          Cpan[(size_t)row * Kpad + col] = bf_rne(acc[mf][nf][r]);
        }
      }
    }
  }
}

// ---------------------------------------------------------------------------
// Fused TU GEMM, 128x128 tile: T = A@Bt^T (bf16), P = A@Bp^T + b_U1 (bf16).
// ---------------------------------------------------------------------------
template<int KD>
__global__ __launch_bounds__(256)
void gemm_tu(const ushort* __restrict__ A, const ushort* __restrict__ Bt_,
             const ushort* __restrict__ Bp_, const float* __restrict__ bias,
             ushort* __restrict__ Tout, ushort* __restrict__ Pout) {
  constexpr int TS = KD / 32;
  __shared__ ushort As[2][4096];
  __shared__ ushort Bt[2][4096];
  __shared__ ushort Bp[2][4096];
  const int tid  = threadIdx.x;
  const int lane = tid & 63;
  const int w    = tid >> 6;
  const int wr   = w >> 1, wc = w & 1;
  const int m0   = blockIdx.x * 128;
  const int n0   = blockIdx.y * 128;
  const int arow = tid >> 2;
  const int acol = (tid & 3) * 8;
  const int fr   = lane & 15;
  const int fq   = lane >> 4;

  f32x4 accT[4][4] = {};
  f32x4 accP[4][4] = {};

  auto stage = [&](int kk, int db) {
#pragma unroll
    for (int i = 0; i < 2; ++i) {
      const ushort* ga = A + (size_t)(m0 + arow + 64 * i) * KD + kk + acol;
      __builtin_amdgcn_global_load_lds((gvoid_t*)ga,
          (lvoid_t*)(&As[db][i * 2048 + w * 512]), 16, 0, 0);
      const ushort* gt = Bt_ + (size_t)(n0 + arow + 64 * i) * KD + kk + acol;
      __builtin_amdgcn_global_load_lds((gvoid_t*)gt,
          (lvoid_t*)(&Bt[db][i * 2048 + w * 512]), 16, 0, 0);
      const ushort* gp = Bp_ + (size_t)(n0 + arow + 64 * i) * KD + kk + acol;
      __builtin_amdgcn_global_load_lds((gvoid_t*)gp,
          (lvoid_t*)(&Bp[db][i * 2048 + w * 512]), 16, 0, 0);
    }
  };

  stage(0, 0);
  __syncthreads();

#pragma unroll
  for (int ts = 0; ts < TS; ++ts) {
    const int db = ts & 1;
    if (ts + 1 < TS) stage((ts + 1) * 32, db ^ 1);
    bf16x8 bt_[4], bp_[4];
#pragma unroll
    for (int nf = 0; nf < 4; ++nf) {
      bt_[nf] = *reinterpret_cast<const bf16x8*>(&Bt[db][(wc * 64 + nf * 16 + fr) * 32 + fq * 8]);
      bp_[nf] = *reinterpret_cast<const bf16x8*>(&Bp[db][(wc * 64 + nf * 16 + fr) * 32 + fq * 8]);
    }
#pragma unroll
    for (int mf = 0; mf < 4; ++mf) {
      bf16x8 af = *reinterpret_cast<const bf16x8*>(&As[db][(wr * 64 + mf * 16 + fr) * 32 + fq * 8]);
#pragma unroll
      for (int nf = 0; nf < 4; ++nf) {
        accT[mf][nf] = __builtin_amdgcn_mfma_f32_16x16x32_bf16(af, bt_[nf], accT[mf][nf], 0, 0, 0);
        accP[mf][nf] = __builtin_amdgcn_mfma_f32_16x16x32_bf16(af, bp_[nf], accP[mf][nf], 0, 0, 0);
      }
    }
    __syncthreads();
  }

#pragma unroll
  for (int mf = 0; mf < 4; ++mf) {
#pragma unroll
    for (int nf = 0; nf < 4; ++nf) {
      const int col = n0 + wc * 64 + nf * 16 + fr;
      const float bv = bias[col];
#pragma unroll
      for (int r = 0; r < 4; ++r) {
        const int row = m0 + wr * 64 + mf * 16 + fq * 4 + r;
        Tout[(size_t)row * Hd + col] = bf_rne(accT[mf][nf][r]);
        Pout[(size_t)row * Hd + col] = bf_rne(accP[mf][nf][r] + bv);
      }
    }
  }
}

// ---------------------------------------------------------------------------
// Plain MFMA GEMM (128x128), bf16 out — depth-2 T (T only, P not needed).
// ---------------------------------------------------------------------------
__global__ __launch_bounds__(256)
void gemm_t(const ushort* __restrict__ A, const ushort* __restrict__ B,
            ushort* __restrict__ Chi) {
  __shared__ ushort As[2][4096];
  __shared__ ushort Bs[2][4096];
  const int tid  = threadIdx.x;
  const int lane = tid & 63;
  const int w    = tid >> 6;
  const int wr   = w >> 1, wc = w & 1;
  const int m0   = blockIdx.x * 128;
  const int n0   = blockIdx.y * 128;
  const int arow = tid >> 2;
  const int acol = (tid & 3) * 8;
  const int fr   = lane & 15;
  const int fq   = lane >> 4;

  f32x4 acc[4][4] = {};

  auto stage = [&](int kk, int db) {
#pragma unroll
    for (int i = 0; i < 2; ++i) {
      const ushort* ga = A + (size_t)(m0 + arow + 64 * i) * Hd + kk + acol;
      const ushort* gb = B + (size_t)(n0 + arow + 64 * i) * Hd + kk + acol;
      __builtin_amdgcn_global_load_lds((gvoid_t*)ga,
          (lvoid_t*)(&As[db][i * 2048 + w * 512]), 16, 0, 0);
      __builtin_amdgcn_global_load_lds((gvoid_t*)gb,
          (lvoid_t*)(&Bs[db][i * 2048 + w * 512]), 16, 0, 0);
    }
  };

  stage(0, 0);
  __syncthreads();

#pragma unroll
  for (int ts = 0; ts < 8; ++ts) {
    const int db = ts & 1;
    if (ts + 1 < 8) stage((ts + 1) * 32, db ^ 1);
    bf16x8 bfr[4];
#pragma unroll
    for (int nf = 0; nf < 4; ++nf)
      bfr[nf] = *reinterpret_cast<const bf16x8*>(&Bs[db][(wc * 64 + nf * 16 + fr) * 32 + fq * 8]);
#pragma unroll
    for (int mf = 0; mf < 4; ++mf) {
      bf16x8 af = *reinterpret_cast<const bf16x8*>(&As[db][(wr * 64 + mf * 16 + fr) * 32 + fq * 8]);
#pragma unroll
      for (int nf = 0; nf < 4; ++nf)
        acc[mf][nf] = __builtin_amdgcn_mfma_f32_16x16x32_bf16(af, bfr[nf], acc[mf][nf], 0, 0, 0);
    }
    __syncthreads();
  }

#pragma unroll
  for (int mf = 0; mf < 4; ++mf) {
#pragma unroll
    for (int nf = 0; nf < 4; ++nf) {
      const int col = n0 + wc * 64 + nf * 16 + fr;
#pragma unroll
      for (int r = 0; r < 4; ++r) {
        const int row = m0 + wr * 64 + mf * 16 + fq * 4 + r;
        Chi[(size_t)row * Hd + col] = bf_rne(acc[mf][nf][r]);
      }
    }
  }
}

// ---------------------------------------------------------------------------
// Fused gather + 128x256 GEMM, 512 threads, 256 blocks (1/CU):
// Phase 1: gather NEI tile [128][256] into XOR-swizzled LDS (full-row sweeps —
//          32 lanes per 512B row, the proven nei_z access pattern; one pass).
// Phase 2: K-loop NEI@w1b from LDS A-tile (swizzled ds_read), B dbuf staged.
//   FINAL=false: C = relu(P + NEI@w1b)            -> bf16 (next AF)
//   FINAL=true : + second K-loop AF@w1a (A dbuf from global); +bias, fp32 out.
// Numerics identical to materialized-NEI path (same fp32 sum, same bf_rne).
// ---------------------------------------------------------------------------
template<bool FINAL>
__global__ __launch_bounds__(512)
void gemm_k2g(const ushort* __restrict__ T, const ushort* __restrict__ Z,
              const uint* __restrict__ PIdx, const int* __restrict__ num_nbs,
              const ushort* __restrict__ w1b,
              const ushort* __restrict__ AF, const ushort* __restrict__ w1a,
              const ushort* __restrict__ Pin, const float* __restrict__ bias,
              float* __restrict__ Cf, ushort* __restrict__ Chi) {
  __shared__ ushort Atile[128 * 256];        // 64 KB, swizzled: byte ^= (row&7)<<4
  __shared__ ushort Bs[2][256 * 32];         // 32 KB B double-buffer
  __shared__ uint   pkL[128 * MNB];
  __shared__ int    nnL[128];
  const int tid  = threadIdx.x;
  const int lane = tid & 63;
  const int w    = tid >> 6;                 // 0..7
  const int wr   = w >> 1, wc = w & 1;       // wr 0..3 (32-row M band), wc 0..1 (128-col N half)
  const int m0   = blockIdx.x * 128;
  const int fr   = lane & 15;
  const int fq   = lane >> 4;
  const int b    = m0 >> 9;
  const size_t tb = ((size_t)b << 9) * Hd;
  const size_t zb = (size_t)b * NBb * Hd;

  // indices
  for (int i = tid; i < 128 * MNB; i += 512) pkL[i] = PIdx[(size_t)m0 * MNB + i];
  if (tid < 128) nnL[tid] = num_nbs[m0 + tid];

  auto stageB = [&](const ushort* Bp, int kk, int db) {
#pragma unroll
    for (int i = 0; i < 2; ++i) {
      const ushort* g = Bp + (size_t)((tid >> 2) + 128 * i) * Hd + kk + (tid & 3) * 8;
      __builtin_amdgcn_global_load_lds((gvoid_t*)g,
          (lvoid_t*)(&Bs[db][i * 4096 + w * 512]), 16, 0, 0);
    }
  };

  stageB(w1b, 0, 0);                         // overlap first B stage with gather
  __syncthreads();                           // pkL/nnL visible (also drains stageB - fine)

  // ---- Phase 1: gather. 4096 tasks = 128 rows x 32 chunks; 8 per thread. ----
  for (int i = 0; i < 8; ++i) {
    const int task = tid + i * 512;
    const int row  = task >> 5;              // 0..127
    const int ch   = task & 31;              // 16B chunk (8 bf16)
    const int nn   = nnL[row];
    const int h0   = ch * 8;
    float a[8] = {};
#pragma unroll
    for (int h5 = 0; h5 < 2; ++h5) {
      uint4 tv[5], zv[5];
#pragma unroll
      for (int j5 = 0; j5 < 5; ++j5) {
        const int j = h5 * 5 + j5;
        uint pk = pkL[row * MNB + j];
        pk = (j < nn) ? pk : pkL[row * MNB];
        tv[j5] = *reinterpret_cast<const uint4*>(&T[tb + (size_t)(pk >> 16) * Hd + h0]);
        zv[j5] = *reinterpret_cast<const uint4*>(&Z[zb + (size_t)(pk & 0xffffu) * Hd + h0]);
      }
#pragma unroll
      for (int j5 = 0; j5 < 5; ++j5) {
        const int j = h5 * 5 + j5;
        const uint tw[4] = {tv[j5].x, tv[j5].y, tv[j5].z, tv[j5].w};
        const uint zw[4] = {zv[j5].x, zv[j5].y, zv[j5].z, zv[j5].w};
        if (j < nn) {
#pragma unroll
          for (int q = 0; q < 4; ++q) {
            a[q * 2]     += fmaxf(__uint_as_float(tw[q] << 16) + __uint_as_float(zw[q] << 16), 0.f);
            a[q * 2 + 1] += fmaxf(__uint_as_float(tw[q] & 0xffff0000u) + __uint_as_float(zw[q] & 0xffff0000u), 0.f);
          }
        }
      }
    }
    uint4 o;
    o.x = (uint)bf_rne(a[0]) | ((uint)bf_rne(a[1]) << 16);
    o.y = (uint)bf_rne(a[2]) | ((uint)bf_rne(a[3]) << 16);
    o.z = (uint)bf_rne(a[4]) | ((uint)bf_rne(a[5]) << 16);
    o.w = (uint)bf_rne(a[6]) | ((uint)bf_rne(a[7]) << 16);
    const int byte = row * 512 + ((ch * 16) ^ ((row & 7) << 4));
    *reinterpret_cast<uint4*>(reinterpret_cast<char*>(Atile) + byte) = o;
  }
  __syncthreads();                           // Atile + Bs[0] ready

  // ---- Phase 2: K-loop(s) ----
  f32x4 acc[2][8] = {};
  constexpr int TS = FINAL ? 16 : 8;

  __shared__ ushort Afs[FINAL ? 2 : 1][FINAL ? 128 * 32 : 1];  // AF dbuf (FINAL only)
  auto stageAF = [&](int kk, int db) {
    const ushort* g = AF + (size_t)(m0 + (tid >> 2)) * Hd + kk + (tid & 3) * 8;
    __builtin_amdgcn_global_load_lds((gvoid_t*)g,
        (lvoid_t*)(&Afs[db][w * 512]), 16, 0, 0);
  };

#pragma unroll
  for (int s = 0; s < TS; ++s) {
    const int db = s & 1;
    if (s + 1 < TS) {                        // prefetch next step
      const int t2 = s + 1;
      if constexpr (FINAL) {
        if (t2 < 8) stageB(w1b, t2 * 32, db ^ 1);
        else { stageB(w1a, (t2 - 8) * 32, db ^ 1); stageAF((t2 - 8) * 32, db ^ 1); }
      } else {
        stageB(w1b, t2 * 32, db ^ 1);
      }
    }
    bf16x8 bfr[8];
#pragma unroll
    for (int nf = 0; nf < 8; ++nf)
      bfr[nf] = *reinterpret_cast<const bf16x8*>(&Bs[db][(wc * 128 + nf * 16 + fr) * 32 + fq * 8]);
#pragma unroll
    for (int mf = 0; mf < 2; ++mf) {
      const int row = wr * 32 + mf * 16 + fr;
      bf16x8 af;
      if (s < 8) {                           // A from swizzled NEI tile
        const int byte = row * 512 + (((s & 7) * 64 + fq * 16) ^ ((row & 7) << 4));
        af = *reinterpret_cast<const bf16x8*>(reinterpret_cast<const char*>(Atile) + byte);
      } else {                               // FINAL: A from AF dbuf
        af = *reinterpret_cast<const bf16x8*>(&Afs[db][row * 32 + fq * 8]);
      }
#pragma unroll
      for (int nf = 0; nf < 8; ++nf)
        acc[mf][nf] = __builtin_amdgcn_mfma_f32_16x16x32_bf16(af, bfr[nf], acc[mf][nf], 0, 0, 0);
    }
    __syncthreads();
  }

  // ---- epilogue ----
#pragma unroll
  for (int mf = 0; mf < 2; ++mf) {
#pragma unroll
    for (int nf = 0; nf < 8; ++nf) {
      const int col = wc * 128 + nf * 16 + fr;
#pragma unroll
      for (int r = 0; r < 4; ++r) {
        const int row = m0 + wr * 32 + mf * 16 + fq * 4 + r;
        if constexpr (FINAL) {
          Cf[(size_t)row * Hd + col] = fmaxf(acc[mf][nf][r] + bias[col], 0.f);
        } else {
          const float v = fmaxf(acc[mf][nf][r] + bf_f(Pin[(size_t)row * Hd + col]), 0.f);
          Chi[(size_t)row * Hd + col] = bf_rne(v);
        }
      }
    }
  }
}

extern "C" void kernel_launch(void* const* d_in, const int* in_sizes, int n_in,
                              void* d_out, int out_size, void* d_ws, size_t ws_size,
                              hipStream_t stream) {
  const float* input_atom = (const float*)d_in[0];
  const float* input_bond = (const float*)d_in[1];
  const int*   atom_graph = (const int*)d_in[2];
  const int*   bond_graph = (const int*)d_in[3];
  const int*   num_nbs    = (const int*)d_in[4];
  const float* W_atom     = (const float*)d_in[5];
  const float* W_U2       = (const float*)d_in[6];
  const float* b_U2       = (const float*)d_in[7];
  const float* W_U1       = (const float*)d_in[8];
  const float* b_U1       = (const float*)d_in[9];

  const size_t SL = (size_t)Mrows * Hd;            // 8,388,608 ushorts
  // ws (~61.4 MB): AFa | Tbuf | PIdx | panels | wabf | wc2T | wc1T | Apadh | Z
  ushort* AFa  = (ushort*)d_ws;
  ushort* Tbuf = AFa + SL;                         // T in ws (FINAL writes all of d_out)
  uint*   PIdx = (uint*)(Tbuf + SL);
  ushort* w2h  = (ushort*)(PIdx + (size_t)Mrows * MNB);
  ushort* w1ah = w2h  + 256 * 256;
  ushort* w1bh = w1ah + 256 * 256;
  ushort* wabf = w1bh + 256 * 256;
  ushort* wc2T = wabf + Kpad * Hd;
  ushort* wc1T = wc2T + Hd * Kpad;
  ushort* Apadh= wc1T + Hd * Kpad;
  ushort* Zbuf = Apadh + (size_t)Mrows * Kpad;

  ushort* Pbf = (ushort*)d_out + SL;               // P in d_out hi half (depths 0,1)

  const dim3 blk(256);
  const dim3 gG(Mrows / 128, Hd / 128);            // (256, 2)
  const dim3 gK(Mrows / 128, 1);                   // (256, 1) fused gather-GEMM

  megaprep<<<S0 + S1 + S2 + S3 + S4, blk, 0, stream>>>(
      input_atom, input_bond, atom_graph, bond_graph, W_atom, W_U2, b_U2, W_U1,
      Apadh, Zbuf, PIdx, w2h, w1ah, w1bh, wabf);

  gemm_wcomb<<<dim3(2, 2), blk, 0, stream>>>(w2h, w1ah, wabf, wc2T, wc1T);

  // ---- depth 0 (embed folded): TU on Apadh (K=96 Wcomb panels) ----
  gemm_tu<Kpad><<<gG, blk, 0, stream>>>(Apadh, wc2T, wc1T, b_U1, Tbuf, Pbf);
  gemm_k2g<false><<<gK, 512, 0, stream>>>(Tbuf, Zbuf, PIdx, num_nbs, w1bh,
                                          nullptr, nullptr, Pbf, nullptr,
                                          nullptr, AFa);

  // ---- depth 1 ----
  gemm_tu<Hd><<<gG, blk, 0, stream>>>(AFa, w2h, w1ah, b_U1, Tbuf, Pbf);
  gemm_k2g<false><<<gK, 512, 0, stream>>>(Tbuf, Zbuf, PIdx, num_nbs, w1bh,
                                          nullptr, nullptr, Pbf, nullptr,
                                          nullptr, AFa);

  // ---- depth 2 (exact fp32 output path) ----
  gemm_t<<<gG, blk, 0, stream>>>(AFa, w2h, Tbuf);
  gemm_k2g<true><<<gK, 512, 0, stream>>>(Tbuf, Zbuf, PIdx, num_nbs, w1bh,
                                         AFa, w1ah, nullptr, b_U1,
                                         (float*)d_out, nullptr);
  // d_out holds the final atom_features (fp32).
}

// Round 13
// 173.422 us; speedup vs baseline: 1.0256x; 1.0256x over previous
//
#include <hip/hip_runtime.h>

// Problem constants (WLN_Edit): B=64, N=512, NB=600, A=89, E=5, H=256, MAX_NB=10, DEPTH=3
constexpr int Bb   = 64;
constexpr int Nn   = 512;
constexpr int NBb  = 600;
constexpr int Ad   = 89;
constexpr int Ed   = 5;
constexpr int Hd   = 256;
constexpr int MNB  = 10;
constexpr int Mrows  = Bb * Nn;    // 32768
constexpr int NBrows = Bb * NBb;   // 38400
constexpr int Kpad   = 96;

typedef __bf16 bf16x8 __attribute__((ext_vector_type(8)));
typedef float  f32x4  __attribute__((ext_vector_type(4)));

typedef __attribute__((address_space(1))) const void gvoid_t;
typedef __attribute__((address_space(3))) void lvoid_t;

__device__ inline ushort bf_rne(float x) {
  unsigned u = __float_as_uint(x);
  unsigned r = (u + 0x7fffu + ((u >> 16) & 1u)) >> 16;
  return (ushort)r;
}
__device__ inline float bf_f(ushort h) { return __uint_as_float(((unsigned)h) << 16); }

// ---------------------------------------------------------------------------
// Mega-prep (no LDS): S0 Apadh, S1 Z, S2 PIdx, S3 weight panels, S4 wabf.
// ---------------------------------------------------------------------------
constexpr int S0 = Mrows * Kpad / 256;   // 12288
constexpr int S1 = NBrows / 8;           // 4800
constexpr int S2 = Mrows * MNB / 256;    // 1280
constexpr int S3 = 256;
constexpr int S4 = Kpad * Hd / 256;      // 96

__global__ __launch_bounds__(256)
void megaprep(const float* __restrict__ input_atom, const float* __restrict__ input_bond,
              const int* __restrict__ atom_graph, const int* __restrict__ bond_graph,
              const float* __restrict__ W_atom, const float* __restrict__ W_U2,
              const float* __restrict__ b_U2, const float* __restrict__ W_U1,
              ushort* __restrict__ Apadh, ushort* __restrict__ Z, uint* __restrict__ PIdx,
              ushort* __restrict__ w2h, ushort* __restrict__ w1ah, ushort* __restrict__ w1bh,
              ushort* __restrict__ wabf) {
  const int blk = blockIdx.x;
  const int tid = threadIdx.x;
  if (blk < S0) {                                   // conv_atom
    const int e = blk * 256 + tid;
    const int m = e / Kpad, c = e - m * Kpad;
    Apadh[e] = bf_rne(c < Ad ? input_atom[(size_t)m * Ad + c] : 0.f);
  } else if (blk < S0 + S1) {                       // zprep
    const int r0 = (blk - S0) * 8;
    const int h = tid;
    float w[Ed];
#pragma unroll
    for (int e = 0; e < Ed; ++e) w[e] = W_U2[(size_t)(Hd + e) * Hd + h];
    const float b2 = b_U2[h];
#pragma unroll
    for (int j = 0; j < 8; ++j) {
      const int r = r0 + j;
      const float* bp = input_bond + (size_t)r * Ed;
      float d = b2;
#pragma unroll
      for (int e = 0; e < Ed; ++e) d = fmaf(bp[e], w[e], d);
      Z[(size_t)r * Hd + h] = bf_rne(d);
    }
  } else if (blk < S0 + S1 + S2) {                  // idxpack
    const int i = (blk - S0 - S1) * 256 + tid;
    const uint ai = (uint)atom_graph[(size_t)i * 2 + 1];
    const uint bi = (uint)bond_graph[(size_t)i * 2 + 1];
    PIdx[i] = (ai << 16) | bi;
  } else if (blk < S0 + S1 + S2 + S3) {             // transposed weight panels
    const int n = blk - S0 - S1 - S2;
    const int k = tid;
    const size_t o = (size_t)n * 256 + k;
    w2h[o]  = bf_rne(W_U2[(size_t)k * Hd + n]);
    w1ah[o] = bf_rne(W_U1[(size_t)k * Hd + n]);
    w1bh[o] = bf_rne(W_U1[(size_t)(k + 256) * Hd + n]);
  } else {                                          // S4: wabf row-major copy
    const int e = (blk - S0 - S1 - S2 - S3) * 256 + tid;   // e = a*256+h
    const int a = e >> 8, h = e & 255;
    wabf[e] = bf_rne((a < Ad) ? W_atom[(size_t)a * Hd + h] : 0.f);
  }
}

// ---------------------------------------------------------------------------
// Wcomb GEMM (4 blocks): WcT[n][a] = panel[n][:] . wabf[a][:]  (unchanged).
// ---------------------------------------------------------------------------
__global__ __launch_bounds__(256)
void gemm_wcomb(const ushort* __restrict__ w2h, const ushort* __restrict__ w1ah,
                const ushort* __restrict__ wabf,
                ushort* __restrict__ wc2T, ushort* __restrict__ wc1T) {
  __shared__ ushort As[2][4096];
  __shared__ ushort Bs[2][4096];
  const ushort* Apan = blockIdx.y ? w1ah : w2h;
  ushort*       Cpan = blockIdx.y ? wc1T : wc2T;
  const int tid  = threadIdx.x;
  const int lane = tid & 63;
  const int w    = tid >> 6;
  const int wr   = w >> 1, wc = w & 1;
  const int m0   = blockIdx.x * 128;
  const int arow = tid >> 2;
  const int acol = (tid & 3) * 8;
  const int fr   = lane & 15;
  const int fq   = lane >> 4;

  f32x4 acc[4][4] = {};

  auto stage = [&](int kk, int db) {
#pragma unroll
    for (int i = 0; i < 2; ++i) {
      const ushort* ga = Apan + (size_t)(m0 + arow + 64 * i) * 256 + kk + acol;
      __builtin_amdgcn_global_load_lds((gvoid_t*)ga,
          (lvoid_t*)(&As[db][i * 2048 + w * 512]), 16, 0, 0);
      const int brow = min(arow + 64 * i, Kpad - 1);
      const ushort* gb = wabf + (size_t)brow * 256 + kk + acol;
      __builtin_amdgcn_global_load_lds((gvoid_t*)gb,
          (lvoid_t*)(&Bs[db][i * 2048 + w * 512]), 16, 0, 0);
    }
  };

  stage(0, 0);
  __syncthreads();

#pragma unroll
  for (int ts = 0; ts < 8; ++ts) {
    const int db = ts & 1;
    if (ts + 1 < 8) stage((ts + 1) * 32, db ^ 1);
    bf16x8 bfr[4];
#pragma unroll
    for (int nf = 0; nf < 4; ++nf)
      bfr[nf] = *reinterpret_cast<const bf16x8*>(&Bs[db][(wc * 64 + nf * 16 + fr) * 32 + fq * 8]);
#pragma unroll
    for (int mf = 0; mf < 4; ++mf) {
      bf16x8 af = *reinterpret_cast<const bf16x8*>(&As[db][(wr * 64 + mf * 16 + fr) * 32 + fq * 8]);
#pragma unroll
      for (int nf = 0; nf < 4; ++nf)
        acc[mf][nf] = __builtin_amdgcn_mfma_f32_16x16x32_bf16(af, bfr[nf], acc[mf][nf], 0, 0, 0);
    }
    __syncthreads();
  }

#pragma unroll
  for (int mf = 0; mf < 4; ++mf) {
#pragma unroll
    for (int nf = 0; nf < 4; ++nf) {
      const int col = wc * 64 + nf * 16 + fr;
      if (col < Kpad) {
#pragma unroll
        for (int r = 0; r < 4; ++r) {
          const int row = m0 + wr * 64 + mf * 16 + fq * 4 + r;
          Cpan[(size_t)row * Kpad + col] = bf_rne(acc[mf][nf][r]);
        }
      }
    }
  }
}

// ---------------------------------------------------------------------------
// Fused TU GEMM, 128x128 tile, 1D grid 512 with y-pair + XCD-chunk swizzle:
// both n-halves of an m-tile land on the same XCD -> A's 2nd read is L2-hit.
// ---------------------------------------------------------------------------
template<int KD>
__global__ __launch_bounds__(256)
void gemm_tu(const ushort* __restrict__ A, const ushort* __restrict__ Bt_,
             const ushort* __restrict__ Bp_, const float* __restrict__ bias,
             ushort* __restrict__ Tout, ushort* __restrict__ Pout) {
  constexpr int TS = KD / 32;
  __shared__ ushort As[2][4096];
  __shared__ ushort Bt[2][4096];
  __shared__ ushort Bp[2][4096];
  int f = blockIdx.x;                       // 512 blocks
  f = (f & 7) * 64 + (f >> 3);              // XCD chunk (512%8==0)
  const int m0 = (f >> 1) * 128;
  const int n0 = (f & 1) * 128;
  const int tid  = threadIdx.x;
  const int lane = tid & 63;
  const int w    = tid >> 6;
  const int wr   = w >> 1, wc = w & 1;
  const int arow = tid >> 2;
  const int acol = (tid & 3) * 8;
  const int fr   = lane & 15;
  const int fq   = lane >> 4;

  f32x4 accT[4][4] = {};
  f32x4 accP[4][4] = {};

  auto stage = [&](int kk, int db) {
#pragma unroll
    for (int i = 0; i < 2; ++i) {
      const ushort* ga = A + (size_t)(m0 + arow + 64 * i) * KD + kk + acol;
      __builtin_amdgcn_global_load_lds((gvoid_t*)ga,
          (lvoid_t*)(&As[db][i * 2048 + w * 512]), 16, 0, 0);
      const ushort* gt = Bt_ + (size_t)(n0 + arow + 64 * i) * KD + kk + acol;
      __builtin_amdgcn_global_load_lds((gvoid_t*)gt,
          (lvoid_t*)(&Bt[db][i * 2048 + w * 512]), 16, 0, 0);
      const ushort* gp = Bp_ + (size_t)(n0 + arow + 64 * i) * KD + kk + acol;
      __builtin_amdgcn_global_load_lds((gvoid_t*)gp,
          (lvoid_t*)(&Bp[db][i * 2048 + w * 512]), 16, 0, 0);
    }
  };

  stage(0, 0);
  __syncthreads();

#pragma unroll
  for (int ts = 0; ts < TS; ++ts) {
    const int db = ts & 1;
    if (ts + 1 < TS) stage((ts + 1) * 32, db ^ 1);
    bf16x8 bt_[4], bp_[4];
#pragma unroll
    for (int nf = 0; nf < 4; ++nf) {
      bt_[nf] = *reinterpret_cast<const bf16x8*>(&Bt[db][(wc * 64 + nf * 16 + fr) * 32 + fq * 8]);
      bp_[nf] = *reinterpret_cast<const bf16x8*>(&Bp[db][(wc * 64 + nf * 16 + fr) * 32 + fq * 8]);
    }
#pragma unroll
    for (int mf = 0; mf < 4; ++mf) {
      bf16x8 af = *reinterpret_cast<const bf16x8*>(&As[db][(wr * 64 + mf * 16 + fr) * 32 + fq * 8]);
#pragma unroll
      for (int nf = 0; nf < 4; ++nf) {
        accT[mf][nf] = __builtin_amdgcn_mfma_f32_16x16x32_bf16(af, bt_[nf], accT[mf][nf], 0, 0, 0);
        accP[mf][nf] = __builtin_amdgcn_mfma_f32_16x16x32_bf16(af, bp_[nf], accP[mf][nf], 0, 0, 0);
      }
    }
    __syncthreads();
  }

#pragma unroll
  for (int mf = 0; mf < 4; ++mf) {
#pragma unroll
    for (int nf = 0; nf < 4; ++nf) {
      const int col = n0 + wc * 64 + nf * 16 + fr;
      const float bv = bias[col];
#pragma unroll
      for (int r = 0; r < 4; ++r) {
        const int row = m0 + wr * 64 + mf * 16 + fq * 4 + r;
        Tout[(size_t)row * Hd + col] = bf_rne(accT[mf][nf][r]);
        Pout[(size_t)row * Hd + col] = bf_rne(accP[mf][nf][r] + bv);
      }
    }
  }
}

// ---------------------------------------------------------------------------
// Plain MFMA GEMM (128x128), bf16 out — depth-2 T. Same swizzled 1D grid.
// ---------------------------------------------------------------------------
__global__ __launch_bounds__(256)
void gemm_t(const ushort* __restrict__ A, const ushort* __restrict__ B,
            ushort* __restrict__ Chi) {
  __shared__ ushort As[2][4096];
  __shared__ ushort Bs[2][4096];
  int f = blockIdx.x;                       // 512 blocks
  f = (f & 7) * 64 + (f >> 3);
  const int m0 = (f >> 1) * 128;
  const int n0 = (f & 1) * 128;
  const int tid  = threadIdx.x;
  const int lane = tid & 63;
  const int w    = tid >> 6;
  const int wr   = w >> 1, wc = w & 1;
  const int arow = tid >> 2;
  const int acol = (tid & 3) * 8;
  const int fr   = lane & 15;
  const int fq   = lane >> 4;

  f32x4 acc[4][4] = {};

  auto stage = [&](int kk, int db) {
#pragma unroll
    for (int i = 0; i < 2; ++i) {
      const ushort* ga = A + (size_t)(m0 + arow + 64 * i) * Hd + kk + acol;
      const ushort* gb = B + (size_t)(n0 + arow + 64 * i) * Hd + kk + acol;
      __builtin_amdgcn_global_load_lds((gvoid_t*)ga,
          (lvoid_t*)(&As[db][i * 2048 + w * 512]), 16, 0, 0);
      __builtin_amdgcn_global_load_lds((gvoid_t*)gb,
          (lvoid_t*)(&Bs[db][i * 2048 + w * 512]), 16, 0, 0);
    }
  };

  stage(0, 0);
  __syncthreads();

#pragma unroll
  for (int ts = 0; ts < 8; ++ts) {
    const int db = ts & 1;
    if (ts + 1 < 8) stage((ts + 1) * 32, db ^ 1);
    bf16x8 bfr[4];
#pragma unroll
    for (int nf = 0; nf < 4; ++nf)
      bfr[nf] = *reinterpret_cast<const bf16x8*>(&Bs[db][(wc * 64 + nf * 16 + fr) * 32 + fq * 8]);
#pragma unroll
    for (int mf = 0; mf < 4; ++mf) {
      bf16x8 af = *reinterpret_cast<const bf16x8*>(&As[db][(wr * 64 + mf * 16 + fr) * 32 + fq * 8]);
#pragma unroll
      for (int nf = 0; nf < 4; ++nf)
        acc[mf][nf] = __builtin_amdgcn_mfma_f32_16x16x32_bf16(af, bfr[nf], acc[mf][nf], 0, 0, 0);
    }
    __syncthreads();
  }

#pragma unroll
  for (int mf = 0; mf < 4; ++mf) {
#pragma unroll
    for (int nf = 0; nf < 4; ++nf) {
      const int col = n0 + wc * 64 + nf * 16 + fr;
#pragma unroll
      for (int r = 0; r < 4; ++r) {
        const int row = m0 + wr * 64 + mf * 16 + fq * 4 + r;
        Chi[(size_t)row * Hd + col] = bf_rne(acc[mf][nf][r]);
      }
    }
  }
}

// ---------------------------------------------------------------------------
// 128x256-tile GEMM, 512 threads, XCD-chunk swizzled grid (256,1):
// m-rows align with nei_z's write XCD -> NEI/P reads are L2-warm.
//   FINAL=false: C = relu(P + NEI@w1b)            -> bf16 (next AF)
//   FINAL=true : C = relu(AF@w1a + NEI@w1b + b)   -> fp32 (d_out)
// ---------------------------------------------------------------------------
template<bool FINAL>
__global__ __launch_bounds__(512)
void gemm_k2(const ushort* __restrict__ NEI, const ushort* __restrict__ w1b,
             const ushort* __restrict__ AF, const ushort* __restrict__ w1a,
             const ushort* __restrict__ Pin, const float* __restrict__ bias,
             float* __restrict__ Cf, ushort* __restrict__ Chi) {
  __shared__ ushort As[2][128 * 32];
  __shared__ ushort Bs[2][256 * 32];
  int f = blockIdx.x;                       // 256 blocks
  f = (f & 7) * 32 + (f >> 3);              // match nei_z's XCD row mapping
  const int m0 = f * 128;
  const int tid  = threadIdx.x;
  const int lane = tid & 63;
  const int w    = tid >> 6;
  const int wr   = w >> 1, wc = w & 1;
  const int fr   = lane & 15;
  const int fq   = lane >> 4;

  f32x4 acc[2][8] = {};

  auto stageA = [&](const ushort* Ap, int kk, int db) {
    const ushort* g = Ap + (size_t)(m0 + (tid >> 2)) * Hd + kk + (tid & 3) * 8;
    __builtin_amdgcn_global_load_lds((gvoid_t*)g,
        (lvoid_t*)(&As[db][w * 512]), 16, 0, 0);
  };
  auto stageB = [&](const ushort* Bp, int kk, int db) {
#pragma unroll
    for (int i = 0; i < 2; ++i) {
      const ushort* g = Bp + (size_t)((tid >> 2) + 128 * i) * Hd + kk + (tid & 3) * 8;
      __builtin_amdgcn_global_load_lds((gvoid_t*)g,
          (lvoid_t*)(&Bs[db][i * 4096 + w * 512]), 16, 0, 0);
    }
  };

  constexpr int TS = FINAL ? 16 : 8;
  if constexpr (FINAL) { stageA(AF, 0, 0); stageB(w1a, 0, 0); }
  else                 { stageA(NEI, 0, 0); stageB(w1b, 0, 0); }
  __syncthreads();

#pragma unroll
  for (int ts = 0; ts < TS; ++ts) {
    const int db = ts & 1;
    if (ts + 1 < TS) {
      const int t2 = ts + 1;
      if constexpr (FINAL) {
        if (t2 < 8) { stageA(AF, t2 * 32, db ^ 1); stageB(w1a, t2 * 32, db ^ 1); }
        else        { stageA(NEI, (t2 - 8) * 32, db ^ 1); stageB(w1b, (t2 - 8) * 32, db ^ 1); }
      } else {
        stageA(NEI, t2 * 32, db ^ 1); stageB(w1b, t2 * 32, db ^ 1);
      }
    }
    bf16x8 bfr[8];
#pragma unroll
    for (int nf = 0; nf < 8; ++nf)
      bfr[nf] = *reinterpret_cast<const bf16x8*>(&Bs[db][(wc * 128 + nf * 16 + fr) * 32 + fq * 8]);
#pragma unroll
    for (int mf = 0; mf < 2; ++mf) {
      bf16x8 af = *reinterpret_cast<const bf16x8*>(&As[db][(wr * 32 + mf * 16 + fr) * 32 + fq * 8]);
#pragma unroll
      for (int nf = 0; nf < 8; ++nf)
        acc[mf][nf] = __builtin_amdgcn_mfma_f32_16x16x32_bf16(af, bfr[nf], acc[mf][nf], 0, 0, 0);
    }
    __syncthreads();
  }

#pragma unroll
  for (int mf = 0; mf < 2; ++mf) {
#pragma unroll
    for (int nf = 0; nf < 8; ++nf) {
      const int col = wc * 128 + nf * 16 + fr;
#pragma unroll
      for (int r = 0; r < 4; ++r) {
        const int row = m0 + wr * 32 + mf * 16 + fq * 4 + r;
        if constexpr (FINAL) {
          Cf[(size_t)row * Hd + col] = fmaxf(acc[mf][nf][r] + bias[col], 0.f);
        } else {
          const float v = fmaxf(acc[mf][nf][r] + bf_f(Pin[(size_t)row * Hd + col]), 0.f);
          Chi[(size_t)row * Hd + col] = bf_rne(v);
        }
      }
    }
  }
}

// ---------------------------------------------------------------------------
// nei: NEI[m,h] = sum_{k<nn} relu(T[ai[k]] + Z[bi[k]]).
// PREDICATED gathers: loads only issued for valid neighbors (avg 5.5/10) —
// throughput-bound on L2, so skipping invalid loads cuts ~45% of traffic.
// Numerically identical (accumulate was already guarded).
// ---------------------------------------------------------------------------
__global__ __launch_bounds__(256)
void nei_z(const ushort* __restrict__ T, const ushort* __restrict__ Z,
           const uint* __restrict__ PIdx, const int* __restrict__ num_nbs,
           ushort* __restrict__ NEI) {
  const int ho = threadIdx.x & 31;
  const int rp = threadIdx.x >> 5;
  int bid = blockIdx.x;
  bid = (bid & 7) * (gridDim.x >> 3) + (bid >> 3);   // XCD swizzle (4096%8==0)
  const int m = bid * 8 + rp;
  const int b = m >> 9;
  const int h0 = ho * 8;
  const int nn = num_nbs[m];

  uint pk[MNB];
#pragma unroll
  for (int q = 0; q < 5; ++q) {
    const uint2 u = *reinterpret_cast<const uint2*>(&PIdx[(size_t)m * MNB + q * 2]);
    pk[q * 2] = u.x; pk[q * 2 + 1] = u.y;
  }

  float acc[8] = {};
#pragma unroll
  for (int ch = 0; ch < 2; ++ch) {
    uint4 tv[5], zv[5];
#pragma unroll
    for (int k5 = 0; k5 < 5; ++k5) {     // predicated loads — masked lanes skip
      const int k = ch * 5 + k5;
      if (k < nn) {
        const uint p = pk[k];
        tv[k5] = *reinterpret_cast<const uint4*>(&T[(((size_t)b << 9) + (p >> 16)) * Hd + h0]);
        zv[k5] = *reinterpret_cast<const uint4*>(&Z[((size_t)b * NBb + (p & 0xffffu)) * Hd + h0]);
      }
    }
#pragma unroll
    for (int k5 = 0; k5 < 5; ++k5) {
      const int k = ch * 5 + k5;
      if (k < nn) {
        const uint tw[4] = {tv[k5].x, tv[k5].y, tv[k5].z, tv[k5].w};
        const uint zw[4] = {zv[k5].x, zv[k5].y, zv[k5].z, zv[k5].w};
#pragma unroll
        for (int q = 0; q < 4; ++q) {
          acc[q * 2]     += fmaxf(__uint_as_float(tw[q] << 16) + __uint_as_float(zw[q] << 16), 0.f);
          acc[q * 2 + 1] += fmaxf(__uint_as_float(tw[q] & 0xffff0000u) + __uint_as_float(zw[q] & 0xffff0000u), 0.f);
        }
      }
    }
  }
  uint4 o;
  o.x = (uint)bf_rne(acc[0]) | ((uint)bf_rne(acc[1]) << 16);
  o.y = (uint)bf_rne(acc[2]) | ((uint)bf_rne(acc[3]) << 16);
  o.z = (uint)bf_rne(acc[4]) | ((uint)bf_rne(acc[5]) << 16);
  o.w = (uint)bf_rne(acc[6]) | ((uint)bf_rne(acc[7]) << 16);
  *reinterpret_cast<uint4*>(&NEI[(size_t)m * Hd + h0]) = o;
}

extern "C" void kernel_launch(void* const* d_in, const int* in_sizes, int n_in,
                              void* d_out, int out_size, void* d_ws, size_t ws_size,
                              hipStream_t stream) {
  const float* input_atom = (const float*)d_in[0];
  const float* input_bond = (const float*)d_in[1];
  const int*   atom_graph = (const int*)d_in[2];
  const int*   bond_graph = (const int*)d_in[3];
  const int*   num_nbs    = (const int*)d_in[4];
  const float* W_atom     = (const float*)d_in[5];
  const float* W_U2       = (const float*)d_in[6];
  const float* b_U2       = (const float*)d_in[7];
  const float* W_U1       = (const float*)d_in[8];
  const float* b_U1       = (const float*)d_in[9];

  const size_t SL = (size_t)Mrows * Hd;            // 8,388,608 ushorts
  // ws (~61.4 MB): AFa | AFb(NEI) | PIdx | panels | wabf | wc2T | wc1T | Apadh | Z
  ushort* AFa  = (ushort*)d_ws;
  ushort* AFb  = AFa + SL;
  uint*   PIdx = (uint*)(AFb + SL);
  ushort* w2h  = (ushort*)(PIdx + (size_t)Mrows * MNB);
  ushort* w1ah = w2h  + 256 * 256;
  ushort* w1bh = w1ah + 256 * 256;
  ushort* wabf = w1bh + 256 * 256;
  ushort* wc2T = wabf + Kpad * Hd;
  ushort* wc1T = wc2T + Hd * Kpad;
  ushort* Apadh= wc1T + Hd * Kpad;
  ushort* Zbuf = Apadh + (size_t)Mrows * Kpad;

  ushort* Tbf = (ushort*)d_out;                    // d_out lo half: T (bf16)
  ushort* Pbf = Tbf + SL;                          // d_out hi half: P (bf16)

  const dim3 blk(256);
  const dim3 gG1(Mrows / 128 * 2);                 // 512, 1D swizzled
  const dim3 gK(Mrows / 128);                      // 256, 1D swizzled

  megaprep<<<S0 + S1 + S2 + S3 + S4, blk, 0, stream>>>(
      input_atom, input_bond, atom_graph, bond_graph, W_atom, W_U2, b_U2, W_U1,
      Apadh, Zbuf, PIdx, w2h, w1ah, w1bh, wabf);

  gemm_wcomb<<<dim3(2, 2), blk, 0, stream>>>(w2h, w1ah, wabf, wc2T, wc1T);

  // ---- depth 0 (embed folded): TU on Apadh (K=96 Wcomb panels) ----
  gemm_tu<Kpad><<<gG1, blk, 0, stream>>>(Apadh, wc2T, wc1T, b_U1, Tbf, Pbf);
  nei_z<<<Mrows / 8, blk, 0, stream>>>(Tbf, Zbuf, PIdx, num_nbs, AFb);
  gemm_k2<false><<<gK, 512, 0, stream>>>(AFb, w1bh, nullptr, nullptr, Pbf,
                                         nullptr, nullptr, AFa);

  // ---- depth 1 ----
  gemm_tu<Hd><<<gG1, blk, 0, stream>>>(AFa, w2h, w1ah, b_U1, Tbf, Pbf);
  nei_z<<<Mrows / 8, blk, 0, stream>>>(Tbf, Zbuf, PIdx, num_nbs, AFb);
  gemm_k2<false><<<gK, 512, 0, stream>>>(AFb, w1bh, nullptr, nullptr, Pbf,
                                         nullptr, nullptr, AFa);

  // ---- depth 2 (exact fp32 output path) ----
  gemm_t<<<gG1, blk, 0, stream>>>(AFa, w2h, Tbf);
  nei_z<<<Mrows / 8, blk, 0, stream>>>(Tbf, Zbuf, PIdx, num_nbs, AFb);
  gemm_k2<true><<<gK, 512, 0, stream>>>(AFb, w1bh, AFa, w1ah, nullptr, b_U1,
                                        (float*)d_out, nullptr);
  // d_out holds the final atom_features (fp32).
}

// Round 14
// 160.081 us; speedup vs baseline: 1.1111x; 1.0833x over previous
//
#include <hip/hip_runtime.h>

// Problem constants (WLN_Edit): B=64, N=512, NB=600, A=89, E=5, H=256, MAX_NB=10, DEPTH=3
constexpr int Bb   = 64;
constexpr int Nn   = 512;
constexpr int NBb  = 600;
constexpr int Ad   = 89;
constexpr int Ed   = 5;
constexpr int Hd   = 256;
constexpr int MNB  = 10;
constexpr int Mrows  = Bb * Nn;    // 32768
constexpr int NBrows = Bb * NBb;   // 38400
constexpr int Kpad   = 96;

typedef __bf16 bf16x8 __attribute__((ext_vector_type(8)));
typedef float  f32x4  __attribute__((ext_vector_type(4)));

typedef __attribute__((address_space(1))) const void gvoid_t;
typedef __attribute__((address_space(3))) void lvoid_t;

__device__ inline ushort bf_rne(float x) {
  unsigned u = __float_as_uint(x);
  unsigned r = (u + 0x7fffu + ((u >> 16) & 1u)) >> 16;
  return (ushort)r;
}
__device__ inline float bf_f(ushort h) { return __uint_as_float(((unsigned)h) << 16); }

// ---------------------------------------------------------------------------
// Mega-prep (no LDS): S0 Apadh, S1 Z, S2 PIdx, S3 weight panels, S4 wabf.
// ---------------------------------------------------------------------------
constexpr int S0 = Mrows * Kpad / 256;   // 12288
constexpr int S1 = NBrows / 8;           // 4800
constexpr int S2 = Mrows * MNB / 256;    // 1280
constexpr int S3 = 256;
constexpr int S4 = Kpad * Hd / 256;      // 96

__global__ __launch_bounds__(256)
void megaprep(const float* __restrict__ input_atom, const float* __restrict__ input_bond,
              const int* __restrict__ atom_graph, const int* __restrict__ bond_graph,
              const float* __restrict__ W_atom, const float* __restrict__ W_U2,
              const float* __restrict__ b_U2, const float* __restrict__ W_U1,
              ushort* __restrict__ Apadh, ushort* __restrict__ Z, uint* __restrict__ PIdx,
              ushort* __restrict__ w2h, ushort* __restrict__ w1ah, ushort* __restrict__ w1bh,
              ushort* __restrict__ wabf) {
  const int blk = blockIdx.x;
  const int tid = threadIdx.x;
  if (blk < S0) {                                   // conv_atom
    const int e = blk * 256 + tid;
    const int m = e / Kpad, c = e - m * Kpad;
    Apadh[e] = bf_rne(c < Ad ? input_atom[(size_t)m * Ad + c] : 0.f);
  } else if (blk < S0 + S1) {                       // zprep
    const int r0 = (blk - S0) * 8;
    const int h = tid;
    float w[Ed];
#pragma unroll
    for (int e = 0; e < Ed; ++e) w[e] = W_U2[(size_t)(Hd + e) * Hd + h];
    const float b2 = b_U2[h];
#pragma unroll
    for (int j = 0; j < 8; ++j) {
      const int r = r0 + j;
      const float* bp = input_bond + (size_t)r * Ed;
      float d = b2;
#pragma unroll
      for (int e = 0; e < Ed; ++e) d = fmaf(bp[e], w[e], d);
      Z[(size_t)r * Hd + h] = bf_rne(d);
    }
  } else if (blk < S0 + S1 + S2) {                  // idxpack
    const int i = (blk - S0 - S1) * 256 + tid;
    const uint ai = (uint)atom_graph[(size_t)i * 2 + 1];
    const uint bi = (uint)bond_graph[(size_t)i * 2 + 1];
    PIdx[i] = (ai << 16) | bi;
  } else if (blk < S0 + S1 + S2 + S3) {             // transposed weight panels
    const int n = blk - S0 - S1 - S2;
    const int k = tid;
    const size_t o = (size_t)n * 256 + k;
    w2h[o]  = bf_rne(W_U2[(size_t)k * Hd + n]);
    w1ah[o] = bf_rne(W_U1[(size_t)k * Hd + n]);
    w1bh[o] = bf_rne(W_U1[(size_t)(k + 256) * Hd + n]);
  } else {                                          // S4: wabf row-major copy
    const int e = (blk - S0 - S1 - S2 - S3) * 256 + tid;   // e = a*256+h
    const int a = e >> 8, h = e & 255;
    wabf[e] = bf_rne((a < Ad) ? W_atom[(size_t)a * Hd + h] : 0.f);
  }
}

// ---------------------------------------------------------------------------
// Wcomb GEMM (4 blocks): WcT[n][a] = panel[n][:] . wabf[a][:]  (r11 exact).
// ---------------------------------------------------------------------------
__global__ __launch_bounds__(256)
void gemm_wcomb(const ushort* __restrict__ w2h, const ushort* __restrict__ w1ah,
                const ushort* __restrict__ wabf,
                ushort* __restrict__ wc2T, ushort* __restrict__ wc1T) {
  __shared__ ushort As[2][4096];
  __shared__ ushort Bs[2][4096];
  const ushort* Apan = blockIdx.y ? w1ah : w2h;
  ushort*       Cpan = blockIdx.y ? wc1T : wc2T;
  const int tid  = threadIdx.x;
  const int lane = tid & 63;
  const int w    = tid >> 6;
  const int wr   = w >> 1, wc = w & 1;
  const int m0   = blockIdx.x * 128;
  const int arow = tid >> 2;
  const int acol = (tid & 3) * 8;
  const int fr   = lane & 15;
  const int fq   = lane >> 4;

  f32x4 acc[4][4] = {};

  auto stage = [&](int kk, int db) {
#pragma unroll
    for (int i = 0; i < 2; ++i) {
      const ushort* ga = Apan + (size_t)(m0 + arow + 64 * i) * 256 + kk + acol;
      __builtin_amdgcn_global_load_lds((gvoid_t*)ga,
          (lvoid_t*)(&As[db][i * 2048 + w * 512]), 16, 0, 0);
      const int brow = min(arow + 64 * i, Kpad - 1);
      const ushort* gb = wabf + (size_t)brow * 256 + kk + acol;
      __builtin_amdgcn_global_load_lds((gvoid_t*)gb,
          (lvoid_t*)(&Bs[db][i * 2048 + w * 512]), 16, 0, 0);
    }
  };

  stage(0, 0);
  __syncthreads();

#pragma unroll
  for (int ts = 0; ts < 8; ++ts) {
    const int db = ts & 1;
    if (ts + 1 < 8) stage((ts + 1) * 32, db ^ 1);
    bf16x8 bfr[4];
#pragma unroll
    for (int nf = 0; nf < 4; ++nf)
      bfr[nf] = *reinterpret_cast<const bf16x8*>(&Bs[db][(wc * 64 + nf * 16 + fr) * 32 + fq * 8]);
#pragma unroll
    for (int mf = 0; mf < 4; ++mf) {
      bf16x8 af = *reinterpret_cast<const bf16x8*>(&As[db][(wr * 64 + mf * 16 + fr) * 32 + fq * 8]);
#pragma unroll
      for (int nf = 0; nf < 4; ++nf)
        acc[mf][nf] = __builtin_amdgcn_mfma_f32_16x16x32_bf16(af, bfr[nf], acc[mf][nf], 0, 0, 0);
    }
    __syncthreads();
  }

#pragma unroll
  for (int mf = 0; mf < 4; ++mf) {
#pragma unroll
    for (int nf = 0; nf < 4; ++nf) {
      const int col = wc * 64 + nf * 16 + fr;
      if (col < Kpad) {
#pragma unroll
        for (int r = 0; r < 4; ++r) {
          const int row = m0 + wr * 64 + mf * 16 + fq * 4 + r;
          Cpan[(size_t)row * Kpad + col] = bf_rne(acc[mf][nf][r]);
        }
      }
    }
  }
}

// ---------------------------------------------------------------------------
// Fused TU GEMM, 128x128 tile (r11 exact, 2D grid): T = A@Bt^T, P = A@Bp^T + b.
// ---------------------------------------------------------------------------
template<int KD>
__global__ __launch_bounds__(256)
void gemm_tu(const ushort* __restrict__ A, const ushort* __restrict__ Bt_,
             const ushort* __restrict__ Bp_, const float* __restrict__ bias,
             ushort* __restrict__ Tout, ushort* __restrict__ Pout) {
  constexpr int TS = KD / 32;
  __shared__ ushort As[2][4096];
  __shared__ ushort Bt[2][4096];
  __shared__ ushort Bp[2][4096];
  const int tid  = threadIdx.x;
  const int lane = tid & 63;
  const int w    = tid >> 6;
  const int wr   = w >> 1, wc = w & 1;
  const int m0   = blockIdx.x * 128;
  const int n0   = blockIdx.y * 128;
  const int arow = tid >> 2;
  const int acol = (tid & 3) * 8;
  const int fr   = lane & 15;
  const int fq   = lane >> 4;

  f32x4 accT[4][4] = {};
  f32x4 accP[4][4] = {};

  auto stage = [&](int kk, int db) {
#pragma unroll
    for (int i = 0; i < 2; ++i) {
      const ushort* ga = A + (size_t)(m0 + arow + 64 * i) * KD + kk + acol;
      __builtin_amdgcn_global_load_lds((gvoid_t*)ga,
          (lvoid_t*)(&As[db][i * 2048 + w * 512]), 16, 0, 0);
      const ushort* gt = Bt_ + (size_t)(n0 + arow + 64 * i) * KD + kk + acol;
      __builtin_amdgcn_global_load_lds((gvoid_t*)gt,
          (lvoid_t*)(&Bt[db][i * 2048 + w * 512]), 16, 0, 0);
      const ushort* gp = Bp_ + (size_t)(n0 + arow + 64 * i) * KD + kk + acol;
      __builtin_amdgcn_global_load_lds((gvoid_t*)gp,
          (lvoid_t*)(&Bp[db][i * 2048 + w * 512]), 16, 0, 0);
    }
  };

  stage(0, 0);
  __syncthreads();

#pragma unroll
  for (int ts = 0; ts < TS; ++ts) {
    const int db = ts & 1;
    if (ts + 1 < TS) stage((ts + 1) * 32, db ^ 1);
    bf16x8 bt_[4], bp_[4];
#pragma unroll
    for (int nf = 0; nf < 4; ++nf) {
      bt_[nf] = *reinterpret_cast<const bf16x8*>(&Bt[db][(wc * 64 + nf * 16 + fr) * 32 + fq * 8]);
      bp_[nf] = *reinterpret_cast<const bf16x8*>(&Bp[db][(wc * 64 + nf * 16 + fr) * 32 + fq * 8]);
    }
#pragma unroll
    for (int mf = 0; mf < 4; ++mf) {
      bf16x8 af = *reinterpret_cast<const bf16x8*>(&As[db][(wr * 64 + mf * 16 + fr) * 32 + fq * 8]);
#pragma unroll
      for (int nf = 0; nf < 4; ++nf) {
        accT[mf][nf] = __builtin_amdgcn_mfma_f32_16x16x32_bf16(af, bt_[nf], accT[mf][nf], 0, 0, 0);
        accP[mf][nf] = __builtin_amdgcn_mfma_f32_16x16x32_bf16(af, bp_[nf], accP[mf][nf], 0, 0, 0);
      }
    }
    __syncthreads();
  }

#pragma unroll
  for (int mf = 0; mf < 4; ++mf) {
#pragma unroll
    for (int nf = 0; nf < 4; ++nf) {
      const int col = n0 + wc * 64 + nf * 16 + fr;
      const float bv = bias[col];
#pragma unroll
      for (int r = 0; r < 4; ++r) {
        const int row = m0 + wr * 64 + mf * 16 + fq * 4 + r;
        Tout[(size_t)row * Hd + col] = bf_rne(accT[mf][nf][r]);
        Pout[(size_t)row * Hd + col] = bf_rne(accP[mf][nf][r] + bv);
      }
    }
  }
}

// ---------------------------------------------------------------------------
// Plain MFMA GEMM (128x128), bf16 out — depth-2 T (r11 exact, 2D grid).
// ---------------------------------------------------------------------------
__global__ __launch_bounds__(256)
void gemm_t(const ushort* __restrict__ A, const ushort* __restrict__ B,
            ushort* __restrict__ Chi) {
  __shared__ ushort As[2][4096];
  __shared__ ushort Bs[2][4096];
  const int tid  = threadIdx.x;
  const int lane = tid & 63;
  const int w    = tid >> 6;
  const int wr   = w >> 1, wc = w & 1;
  const int m0   = blockIdx.x * 128;
  const int n0   = blockIdx.y * 128;
  const int arow = tid >> 2;
  const int acol = (tid & 3) * 8;
  const int fr   = lane & 15;
  const int fq   = lane >> 4;

  f32x4 acc[4][4] = {};

  auto stage = [&](int kk, int db) {
#pragma unroll
    for (int i = 0; i < 2; ++i) {
      const ushort* ga = A + (size_t)(m0 + arow + 64 * i) * Hd + kk + acol;
      const ushort* gb = B + (size_t)(n0 + arow + 64 * i) * Hd + kk + acol;
      __builtin_amdgcn_global_load_lds((gvoid_t*)ga,
          (lvoid_t*)(&As[db][i * 2048 + w * 512]), 16, 0, 0);
      __builtin_amdgcn_global_load_lds((gvoid_t*)gb,
          (lvoid_t*)(&Bs[db][i * 2048 + w * 512]), 16, 0, 0);
    }
  };

  stage(0, 0);
  __syncthreads();

#pragma unroll
  for (int ts = 0; ts < 8; ++ts) {
    const int db = ts & 1;
    if (ts + 1 < 8) stage((ts + 1) * 32, db ^ 1);
    bf16x8 bfr[4];
#pragma unroll
    for (int nf = 0; nf < 4; ++nf)
      bfr[nf] = *reinterpret_cast<const bf16x8*>(&Bs[db][(wc * 64 + nf * 16 + fr) * 32 + fq * 8]);
#pragma unroll
    for (int mf = 0; mf < 4; ++mf) {
      bf16x8 af = *reinterpret_cast<const bf16x8*>(&As[db][(wr * 64 + mf * 16 + fr) * 32 + fq * 8]);
#pragma unroll
      for (int nf = 0; nf < 4; ++nf)
        acc[mf][nf] = __builtin_amdgcn_mfma_f32_16x16x32_bf16(af, bfr[nf], acc[mf][nf], 0, 0, 0);
    }
    __syncthreads();
  }

#pragma unroll
  for (int mf = 0; mf < 4; ++mf) {
#pragma unroll
    for (int nf = 0; nf < 4; ++nf) {
      const int col = n0 + wc * 64 + nf * 16 + fr;
#pragma unroll
      for (int r = 0; r < 4; ++r) {
        const int row = m0 + wr * 64 + mf * 16 + fq * 4 + r;
        Chi[(size_t)row * Hd + col] = bf_rne(acc[mf][nf][r]);
      }
    }
  }
}

// ---------------------------------------------------------------------------
// 128x256-tile GEMM, 512 threads, grid 256 — XCD-aligned with nei_z's writes:
// block g (XCD g&7) handles m-tile (g&7)*32+(g>>3), the rows nei_z just wrote
// on that XCD -> NEI reads are L2-warm. (Only change vs r11.)
//   FINAL=false: C = relu(P + NEI@w1b)            -> bf16 (next AF)
//   FINAL=true : C = relu(AF@w1a + NEI@w1b + b)   -> fp32 (d_out)
// ---------------------------------------------------------------------------
template<bool FINAL>
__global__ __launch_bounds__(512)
void gemm_k2(const ushort* __restrict__ NEI, const ushort* __restrict__ w1b,
             const ushort* __restrict__ AF, const ushort* __restrict__ w1a,
             const ushort* __restrict__ Pin, const float* __restrict__ bias,
             float* __restrict__ Cf, ushort* __restrict__ Chi) {
  __shared__ ushort As[2][128 * 32];
  __shared__ ushort Bs[2][256 * 32];
  int f = blockIdx.x;                       // 256 blocks
  f = (f & 7) * 32 + (f >> 3);              // match nei_z's XCD row mapping
  const int m0 = f * 128;
  const int tid  = threadIdx.x;
  const int lane = tid & 63;
  const int w    = tid >> 6;
  const int wr   = w >> 1, wc = w & 1;
  const int fr   = lane & 15;
  const int fq   = lane >> 4;

  f32x4 acc[2][8] = {};

  auto stageA = [&](const ushort* Ap, int kk, int db) {
    const ushort* g = Ap + (size_t)(m0 + (tid >> 2)) * Hd + kk + (tid & 3) * 8;
    __builtin_amdgcn_global_load_lds((gvoid_t*)g,
        (lvoid_t*)(&As[db][w * 512]), 16, 0, 0);
  };
  auto stageB = [&](const ushort* Bp, int kk, int db) {
#pragma unroll
    for (int i = 0; i < 2; ++i) {
      const ushort* g = Bp + (size_t)((tid >> 2) + 128 * i) * Hd + kk + (tid & 3) * 8;
      __builtin_amdgcn_global_load_lds((gvoid_t*)g,
          (lvoid_t*)(&Bs[db][i * 4096 + w * 512]), 16, 0, 0);
    }
  };

  constexpr int TS = FINAL ? 16 : 8;
  if constexpr (FINAL) { stageA(AF, 0, 0); stageB(w1a, 0, 0); }
  else                 { stageA(NEI, 0, 0); stageB(w1b, 0, 0); }
  __syncthreads();

#pragma unroll
  for (int ts = 0; ts < TS; ++ts) {
    const int db = ts & 1;
    if (ts + 1 < TS) {
      const int t2 = ts + 1;
      if constexpr (FINAL) {
        if (t2 < 8) { stageA(AF, t2 * 32, db ^ 1); stageB(w1a, t2 * 32, db ^ 1); }
        else        { stageA(NEI, (t2 - 8) * 32, db ^ 1); stageB(w1b, (t2 - 8) * 32, db ^ 1); }
      } else {
        stageA(NEI, t2 * 32, db ^ 1); stageB(w1b, t2 * 32, db ^ 1);
      }
    }
    bf16x8 bfr[8];
#pragma unroll
    for (int nf = 0; nf < 8; ++nf)
      bfr[nf] = *reinterpret_cast<const bf16x8*>(&Bs[db][(wc * 128 + nf * 16 + fr) * 32 + fq * 8]);
#pragma unroll
    for (int mf = 0; mf < 2; ++mf) {
      bf16x8 af = *reinterpret_cast<const bf16x8*>(&As[db][(wr * 32 + mf * 16 + fr) * 32 + fq * 8]);
#pragma unroll
      for (int nf = 0; nf < 8; ++nf)
        acc[mf][nf] = __builtin_amdgcn_mfma_f32_16x16x32_bf16(af, bfr[nf], acc[mf][nf], 0, 0, 0);
    }
    __syncthreads();
  }

#pragma unroll
  for (int mf = 0; mf < 2; ++mf) {
#pragma unroll
    for (int nf = 0; nf < 8; ++nf) {
      const int col = wc * 128 + nf * 16 + fr;
#pragma unroll
      for (int r = 0; r < 4; ++r) {
        const int row = m0 + wr * 32 + mf * 16 + fq * 4 + r;
        if constexpr (FINAL) {
          Cf[(size_t)row * Hd + col] = fmaxf(acc[mf][nf][r] + bias[col], 0.f);
        } else {
          const float v = fmaxf(acc[mf][nf][r] + bf_f(Pin[(size_t)row * Hd + col]), 0.f);
          Chi[(size_t)row * Hd + col] = bf_rne(v);
        }
      }
    }
  }
}

// ---------------------------------------------------------------------------
// nei (r11 exact): all 10 gathers issued up-front with clamped indices —
// clamped repeats are same-line L2 hits (cheap); predication regressed (r13).
// ---------------------------------------------------------------------------
__global__ __launch_bounds__(256)
void nei_z(const ushort* __restrict__ T, const ushort* __restrict__ Z,
           const uint* __restrict__ PIdx, const int* __restrict__ num_nbs,
           ushort* __restrict__ NEI) {
  const int ho = threadIdx.x & 31;
  const int rp = threadIdx.x >> 5;
  int bid = blockIdx.x;
  bid = (bid & 7) * (gridDim.x >> 3) + (bid >> 3);   // XCD swizzle (4096%8==0)
  const int m = bid * 8 + rp;
  const int b = m >> 9;
  const int h0 = ho * 8;
  const int nn = num_nbs[m];

  uint pk[MNB];
#pragma unroll
  for (int q = 0; q < 5; ++q) {
    const uint2 u = *reinterpret_cast<const uint2*>(&PIdx[(size_t)m * MNB + q * 2]);
    pk[q * 2] = u.x; pk[q * 2 + 1] = u.y;
  }
  int ai[MNB], bi[MNB];
#pragma unroll
  for (int k = 0; k < MNB; ++k) { ai[k] = (int)(pk[k] >> 16); bi[k] = (int)(pk[k] & 0xffffu); }
#pragma unroll
  for (int k = 1; k < MNB; ++k) {
    ai[k] = (k < nn) ? ai[k] : ai[0];
    bi[k] = (k < nn) ? bi[k] : bi[0];
  }

  float acc[8] = {};
#pragma unroll
  for (int ch = 0; ch < 2; ++ch) {
    uint4 tv[5], zv[5];
#pragma unroll
    for (int k5 = 0; k5 < 5; ++k5) {
      const int k = ch * 5 + k5;
      tv[k5] = *reinterpret_cast<const uint4*>(&T[(((size_t)b << 9) + ai[k]) * Hd + h0]);
      zv[k5] = *reinterpret_cast<const uint4*>(&Z[((size_t)b * NBb + bi[k]) * Hd + h0]);
    }
#pragma unroll
    for (int k5 = 0; k5 < 5; ++k5) {
      const int k = ch * 5 + k5;
      const uint tw[4] = {tv[k5].x, tv[k5].y, tv[k5].z, tv[k5].w};
      const uint zw[4] = {zv[k5].x, zv[k5].y, zv[k5].z, zv[k5].w};
      if (k < nn) {
#pragma unroll
        for (int q = 0; q < 4; ++q) {
          acc[q * 2]     += fmaxf(__uint_as_float(tw[q] << 16) + __uint_as_float(zw[q] << 16), 0.f);
          acc[q * 2 + 1] += fmaxf(__uint_as_float(tw[q] & 0xffff0000u) + __uint_as_float(zw[q] & 0xffff0000u), 0.f);
        }
      }
    }
  }
  uint4 o;
  o.x = (uint)bf_rne(acc[0]) | ((uint)bf_rne(acc[1]) << 16);
  o.y = (uint)bf_rne(acc[2]) | ((uint)bf_rne(acc[3]) << 16);
  o.z = (uint)bf_rne(acc[4]) | ((uint)bf_rne(acc[5]) << 16);
  o.w = (uint)bf_rne(acc[6]) | ((uint)bf_rne(acc[7]) << 16);
  *reinterpret_cast<uint4*>(&NEI[(size_t)m * Hd + h0]) = o;
}

extern "C" void kernel_launch(void* const* d_in, const int* in_sizes, int n_in,
                              void* d_out, int out_size, void* d_ws, size_t ws_size,
                              hipStream_t stream) {
  const float* input_atom = (const float*)d_in[0];
  const float* input_bond = (const float*)d_in[1];
  const int*   atom_graph = (const int*)d_in[2];
  const int*   bond_graph = (const int*)d_in[3];
  const int*   num_nbs    = (const int*)d_in[4];
  const float* W_atom     = (const float*)d_in[5];
  const float* W_U2       = (const float*)d_in[6];
  const float* b_U2       = (const float*)d_in[7];
  const float* W_U1       = (const float*)d_in[8];
  const float* b_U1       = (const float*)d_in[9];

  const size_t SL = (size_t)Mrows * Hd;            // 8,388,608 ushorts
  // ws (~61.4 MB): AFa | AFb(NEI) | PIdx | panels | wabf | wc2T | wc1T | Apadh | Z
  ushort* AFa  = (ushort*)d_ws;
  ushort* AFb  = AFa + SL;
  uint*   PIdx = (uint*)(AFb + SL);
  ushort* w2h  = (ushort*)(PIdx + (size_t)Mrows * MNB);
  ushort* w1ah = w2h  + 256 * 256;
  ushort* w1bh = w1ah + 256 * 256;
  ushort* wabf = w1bh + 256 * 256;
  ushort* wc2T = wabf + Kpad * Hd;
  ushort* wc1T = wc2T + Hd * Kpad;
  ushort* Apadh= wc1T + Hd * Kpad;
  ushort* Zbuf = Apadh + (size_t)Mrows * Kpad;

  ushort* Tbf = (ushort*)d_out;                    // d_out lo half: T (bf16)
  ushort* Pbf = Tbf + SL;                          // d_out hi half: P (bf16)

  const dim3 blk(256);
  const dim3 gG(Mrows / 128, Hd / 128);            // (256, 2)
  const dim3 gK(Mrows / 128);                      // 256, XCD-aligned

  megaprep<<<S0 + S1 + S2 + S3 + S4, blk, 0, stream>>>(
      input_atom, input_bond, atom_graph, bond_graph, W_atom, W_U2, b_U2, W_U1,
      Apadh, Zbuf, PIdx, w2h, w1ah, w1bh, wabf);

  gemm_wcomb<<<dim3(2, 2), blk, 0, stream>>>(w2h, w1ah, wabf, wc2T, wc1T);

  // ---- depth 0 (embed folded): TU on Apadh (K=96 Wcomb panels) ----
  gemm_tu<Kpad><<<gG, blk, 0, stream>>>(Apadh, wc2T, wc1T, b_U1, Tbf, Pbf);
  nei_z<<<Mrows / 8, blk, 0, stream>>>(Tbf, Zbuf, PIdx, num_nbs, AFb);
  gemm_k2<false><<<gK, 512, 0, stream>>>(AFb, w1bh, nullptr, nullptr, Pbf,
                                         nullptr, nullptr, AFa);

  // ---- depth 1 ----
  gemm_tu<Hd><<<gG, blk, 0, stream>>>(AFa, w2h, w1ah, b_U1, Tbf, Pbf);
  nei_z<<<Mrows / 8, blk, 0, stream>>>(Tbf, Zbuf, PIdx, num_nbs, AFb);
  gemm_k2<false><<<gK, 512, 0, stream>>>(AFb, w1bh, nullptr, nullptr, Pbf,
                                         nullptr, nullptr, AFa);

  // ---- depth 2 (exact fp32 output path) ----
  gemm_t<<<gG, blk, 0, stream>>>(AFa, w2h, Tbf);
  nei_z<<<Mrows / 8, blk, 0, stream>>>(Tbf, Zbuf, PIdx, num_nbs, AFb);
  gemm_k2<true><<<gK, 512, 0, stream>>>(AFb, w1bh, AFa, w1ah, nullptr, b_U1,
                                        (float*)d_out, nullptr);
  // d_out holds the final atom_features (fp32).
}